// Round 8
// baseline (307.093 us; speedup 1.0000x reference)
//
#include <hip/hip_runtime.h>
#include <hip/hip_bf16.h>

#define N_NODES   20000
#define N_EDGES   320000
#define DIM       256
#define N_GRAPHS  64
#define N_CLASSES 10
#define N_CH      32                   // feature chunks of 8
#define NP8P      (N_NODES * 8 + 16)   // padded fp8 plane stride; row N_NODES = zeroed DUMMY
#define NP16      (N_NODES * 8)        // ushorts per bf16 plane (320000 B)
#define AGG_THR   512                  // no-LDS agg: high occupancy, many blocks
#define AGG_SLICES 16                  // 512 blocks = 32 chunks x 16 slices
#define SLOT      64                   // fixed CSR slots per node (max deg+1 = 41 << 64)
#define DUMMY     N_NODES              // pad index -> zeroed pad row in plane

// R8: aggs gather straight from global (plane is 160KB = L2-resident; staging it to LDS
// was 40MB redundant reads + barrier + 1 blk/CU cap = Common-mistake #7). Same bytes,
// same slot order, same adds -> bitwise identical. R7 fill-padding reverted (+5us).

typedef short  bf16x8 __attribute__((ext_vector_type(8)));
typedef float  f32x4  __attribute__((ext_vector_type(4)));
typedef float  f32x2  __attribute__((ext_vector_type(2)));

__device__ __forceinline__ float b2f(ushort u) {
    return __uint_as_float(((unsigned)u) << 16);
}
__device__ __forceinline__ ushort f2b(float f) {
    unsigned u = __float_as_uint(f);
    u += 0x7FFF + ((u >> 16) & 1);   // round-to-nearest-even
    return (ushort)(u >> 16);
}
// float -> fp8 e4m3 (OCP on gfx950), single value in byte 0
__device__ __forceinline__ unsigned char f2fp8(float f) {
    return (unsigned char)__builtin_amdgcn_cvt_pk_fp8_f32(f, f, 0, false);
}

// ---------------- prep: x-convert (0..312) + W transpose (313..1080) + CSR prefill
// (1081..1159) + zero fill & plane pad rows (1160..1179). Pure data-parallel writes.
__global__ __launch_bounds__(256) void k_prep(const float* __restrict__ x,
                                              ushort* __restrict__ Xp,
                                              const float* __restrict__ W1,
                                              const float* __restrict__ W2,
                                              const float* __restrict__ W3,
                                              ushort* __restrict__ Wt,
                                              ushort* __restrict__ csr16,
                                              int* __restrict__ fill,
                                              unsigned char* __restrict__ H8p) {
    if (blockIdx.x < 313) {
        // x fp32 row-major -> bf16 chunk planes [c][node][8], LDS transpose
        __shared__ ushort sh[64 * 260];
        int base = blockIdx.x * 64;
        int t = threadIdx.x;
        int col4 = (t & 63) * 4;
#pragma unroll 4
        for (int it = 0; it < 16; ++it) {
            int r = (t >> 6) + it * 4;
            int n = base + r;
            float4 v = (n < N_NODES) ? *(const float4*)(x + (size_t)n * DIM + col4)
                                     : make_float4(0.f, 0.f, 0.f, 0.f);
            ushort4 o; o.x = f2b(v.x); o.y = f2b(v.y); o.z = f2b(v.z); o.w = f2b(v.w);
            *(ushort4*)(sh + r * 260 + col4) = o;
        }
        __syncthreads();
#pragma unroll 4
        for (int it = 0; it < 8; ++it) {
            int q = it * 256 + t;
            int p = q >> 6, nl = q & 63;
            int n = base + nl;
            if (n < N_NODES) {
                uint2 lo = *(uint2*)(sh + nl * 260 + p * 8);
                uint2 hi = *(uint2*)(sh + nl * 260 + p * 8 + 4);
                uint4 o = make_uint4(lo.x, lo.y, hi.x, hi.y);
                *(uint4*)(Xp + (size_t)p * NP16 + (size_t)n * 8) = o;
            }
        }
    } else if (blockIdx.x < 1081) {
        // Wt[w][n*256+k] = bf16(W_w[k*256+n])
        int i = (blockIdx.x - 313) * 256 + threadIdx.x;   // 0..3*65536-1
        int w = i >> 16, r = i & 65535;
        int n = r >> 8, k = r & 255;
        const float* W = (w == 0) ? W1 : (w == 1) ? W2 : W3;
        Wt[i] = f2b(W[k * 256 + n]);
    } else if (blockIdx.x < 1160) {
        // CSR row prefill: slot0 = self-loop, slots 1..63 = DUMMY. degfill overwrites
        // slots 1..deg. A row is 64 ushorts = 128 B = EXACTLY 8 uint4.
        int row = (blockIdx.x - 1081) * 256 + threadIdx.x;
        if (row < N_NODES) {
            uint4* p = (uint4*)(csr16 + (size_t)row * SLOT);
            unsigned dd = (unsigned)DUMMY | ((unsigned)DUMMY << 16);
            uint4 vd = make_uint4(dd, dd, dd, dd);
            p[0] = make_uint4((unsigned)row | ((unsigned)DUMMY << 16), dd, dd, dd);
#pragma unroll
            for (int q = 1; q < 8; ++q) p[q] = vd;
        }
    } else {
        // zero degree counters + zero the 32 plane pad rows (gemm never writes them)
        int i = (blockIdx.x - 1160) * 256 + threadIdx.x;
        if (i < N_NODES / 4) ((int4*)fill)[i] = make_int4(0, 0, 0, 0);
        else if (i < N_NODES / 4 + N_CH) {
            int pl = i - N_NODES / 4;
            *(uint2*)(H8p + (size_t)pl * NP8P + (size_t)N_NODES * 8) = make_uint2(0u, 0u);
        }
    }
}

// ---------------- degfill: EXACT R0 kernel (ordering preserved) ----------------
__global__ void k_degfill(const int* __restrict__ src, const int* __restrict__ dst,
                          int* __restrict__ fill, ushort* __restrict__ csr16) {
    int e = blockIdx.x * 256 + threadIdx.x;
    if (e >= N_EDGES) return;
    int s = src[e], d = dst[e];
    int pos = atomicAdd(&fill[d], 1);
    if (pos < SLOT - 1) csr16[d * SLOT + 1 + pos] = (ushort)s;
}

// ---------------- GEMM: fp8 planes = fp8(dinv[row] * (Xp @ W)), 2 tiles/block ----------------
__global__ __launch_bounds__(256) void k_gemm(const ushort* __restrict__ Xp,
                                              const ushort* __restrict__ Wt,
                                              const int* __restrict__ fill,
                                              unsigned char* __restrict__ H8p) {
    int wave = threadIdx.x >> 6;
    int lane = threadIdx.x & 63;
    int m0 = blockIdx.x * 32;            // 625 blocks
    int n0 = wave * 64;
    int rl = lane & 15;
    int kq = (lane >> 4) * 8;

    f32x4 acc0[4] = {}, acc1[4] = {};

#pragma unroll
    for (int kk = 0; kk < 8; ++kk) {
        int k0 = kk * 32;
        int p = (k0 + kq) >> 3;
        const ushort* xp = Xp + (size_t)p * NP16;
        bf16x8 a0 = *(const bf16x8*)(xp + (size_t)(m0 + rl) * 8);
        bf16x8 a1 = *(const bf16x8*)(xp + (size_t)(m0 + 16 + rl) * 8);
#pragma unroll
        for (int nb = 0; nb < 4; ++nb) {
            const ushort* bptr = Wt + (size_t)(n0 + nb * 16 + rl) * DIM + k0 + kq;
            bf16x8 b = *(const bf16x8*)bptr;
            acc0[nb] = __builtin_amdgcn_mfma_f32_16x16x32_bf16(a0, b, acc0[nb], 0, 0, 0);
            acc1[nb] = __builtin_amdgcn_mfma_f32_16x16x32_bf16(a1, b, acc1[nb], 0, 0, 0);
        }
    }
    int crow0 = m0 + (lane >> 4) * 4;
    int crow1 = crow0 + 16;
    float d00 = rsqrtf((float)fill[crow0 + 0] + 1.0f);
    float d01 = rsqrtf((float)fill[crow0 + 1] + 1.0f);
    float d02 = rsqrtf((float)fill[crow0 + 2] + 1.0f);
    float d03 = rsqrtf((float)fill[crow0 + 3] + 1.0f);
    float d10 = rsqrtf((float)fill[crow1 + 0] + 1.0f);
    float d11 = rsqrtf((float)fill[crow1 + 1] + 1.0f);
    float d12 = rsqrtf((float)fill[crow1 + 2] + 1.0f);
    float d13 = rsqrtf((float)fill[crow1 + 3] + 1.0f);
#pragma unroll
    for (int nb = 0; nb < 4; ++nb) {
        int col = n0 + nb * 16 + rl;
        size_t base = (size_t)(col >> 3) * NP8P + (col & 7);
        H8p[base + (size_t)(crow0 + 0) * 8] = f2fp8(acc0[nb][0] * d00);
        H8p[base + (size_t)(crow0 + 1) * 8] = f2fp8(acc0[nb][1] * d01);
        H8p[base + (size_t)(crow0 + 2) * 8] = f2fp8(acc0[nb][2] * d02);
        H8p[base + (size_t)(crow0 + 3) * 8] = f2fp8(acc0[nb][3] * d03);
        H8p[base + (size_t)(crow1 + 0) * 8] = f2fp8(acc1[nb][0] * d10);
        H8p[base + (size_t)(crow1 + 1) * 8] = f2fp8(acc1[nb][1] * d11);
        H8p[base + (size_t)(crow1 + 2) * 8] = f2fp8(acc1[nb][2] * d12);
        H8p[base + (size_t)(crow1 + 3) * 8] = f2fp8(acc1[nb][3] * d13);
    }
}

// ---------------- aggregation: direct L2 gather from padded fp8 plane (no LDS) ----------------
// Per block the gather working set is its own 160KB plane -> L2-resident. Same bytes,
// same ascending slot order, same packed adds as the staged version -> bitwise identical.
__global__ __launch_bounds__(AGG_THR) void k_agg(
    const unsigned char* __restrict__ H8p, const int* __restrict__ fill,
    const ushort* __restrict__ csr16, const float* __restrict__ bias,
    const ushort* __restrict__ prevp, ushort* __restrict__ outp, int mode) {
    int tid = threadIdx.x;
    int c  = blockIdx.x & 31;                    // chunk
    int sl = blockIdx.x >> 5;                    // dst slice 0..AGG_SLICES-1
    const unsigned char* plane = H8p + (size_t)c * NP8P;

    int fo = c * 8;
    f32x2 B0 = {bias[fo + 0], bias[fo + 1]}, B1 = {bias[fo + 2], bias[fo + 3]};
    f32x2 B2 = {bias[fo + 4], bias[fo + 5]}, B3 = {bias[fo + 6], bias[fo + 7]};

    const int ROWS = N_NODES / AGG_SLICES;       // 1250
    int dend = sl * ROWS + ROWS;
    for (int d = sl * ROWS + tid; d < dend; d += AGG_THR) {
        int deg = fill[d];
        int len = deg + 1; if (len > SLOT) len = SLOT;
        int rl = (len + 3) & ~3;
        const ushort* row = csr16 + (size_t)d * SLOT;

        uint4 pv;
        if (mode == 1) pv = *(const uint4*)(prevp + (size_t)c * NP16 + (size_t)d * 8);

        f32x2 A0 = {0.f, 0.f}, A1 = {0.f, 0.f}, A2 = {0.f, 0.f}, A3 = {0.f, 0.f};

        // per packed-u32 w = 2 slots; per slot: 4 cvt_pk + 4 pk_add (order preserved)
        auto do2 = [&](unsigned w) {
            int i0 = w & 0xFFFF, i1 = w >> 16;
            uint2 v0 = *(const uint2*)(plane + (size_t)i0 * 8);
            uint2 v1 = *(const uint2*)(plane + (size_t)i1 * 8);
            f32x2 lo, hi;
            lo = __builtin_amdgcn_cvt_pk_f32_fp8(v0.x, false);
            hi = __builtin_amdgcn_cvt_pk_f32_fp8(v0.x, true);
            A0 += lo; A1 += hi;
            lo = __builtin_amdgcn_cvt_pk_f32_fp8(v0.y, false);
            hi = __builtin_amdgcn_cvt_pk_f32_fp8(v0.y, true);
            A2 += lo; A3 += hi;
            lo = __builtin_amdgcn_cvt_pk_f32_fp8(v1.x, false);
            hi = __builtin_amdgcn_cvt_pk_f32_fp8(v1.x, true);
            A0 += lo; A1 += hi;
            lo = __builtin_amdgcn_cvt_pk_f32_fp8(v1.y, false);
            hi = __builtin_amdgcn_cvt_pk_f32_fp8(v1.y, true);
            A2 += lo; A3 += hi;
        };

        int e = 0;
        for (; e + 8 <= rl; e += 8) {
            uint4 m = *(const uint4*)(row + e);
            do2(m.x); do2(m.y); do2(m.z); do2(m.w);
        }
        if (e < rl) {                           // remaining 4 slots
            uint2 m = *(const uint2*)(row + e);
            do2(m.x); do2(m.y);
        }

        float dv = rsqrtf((float)deg + 1.0f);
        f32x2 DV = {dv, dv};
        A0 = A0 * DV + B0; A1 = A1 * DV + B1;
        A2 = A2 * DV + B2; A3 = A3 * DV + B3;
        if (mode == 1) {
            A0 += (f32x2){b2f((ushort)(pv.x & 0xFFFF)), b2f((ushort)(pv.x >> 16))};
            A1 += (f32x2){b2f((ushort)(pv.y & 0xFFFF)), b2f((ushort)(pv.y >> 16))};
            A2 += (f32x2){b2f((ushort)(pv.z & 0xFFFF)), b2f((ushort)(pv.z >> 16))};
            A3 += (f32x2){b2f((ushort)(pv.w & 0xFFFF)), b2f((ushort)(pv.w >> 16))};
        }
        if (mode != 2) {
            A0[0] = fmaxf(A0[0], 0.f); A0[1] = fmaxf(A0[1], 0.f);
            A1[0] = fmaxf(A1[0], 0.f); A1[1] = fmaxf(A1[1], 0.f);
            A2[0] = fmaxf(A2[0], 0.f); A2[1] = fmaxf(A2[1], 0.f);
            A3[0] = fmaxf(A3[0], 0.f); A3[1] = fmaxf(A3[1], 0.f);
        }
        uint4 o;
        o.x = (unsigned)f2b(A0[0]) | ((unsigned)f2b(A0[1]) << 16);
        o.y = (unsigned)f2b(A1[0]) | ((unsigned)f2b(A1[1]) << 16);
        o.z = (unsigned)f2b(A2[0]) | ((unsigned)f2b(A2[1]) << 16);
        o.w = (unsigned)f2b(A3[0]) | ((unsigned)f2b(A3[1]) << 16);
        *(uint4*)(outp + (size_t)c * NP16 + (size_t)d * 8) = o;
    }
}

// ---------------- fused pool + bounds + head (vectorized: uint4 per node-plane) ----------------
__global__ __launch_bounds__(512) void k_poolfinal(const ushort* __restrict__ h3p,
                                                   const int* __restrict__ batch,
                                                   const float* __restrict__ Wc,
                                                   const float* __restrict__ bc,
                                                   float* __restrict__ out) {
    __shared__ float part[512 * 8];          // 16 KB
    __shared__ float pooled[DIM];
    __shared__ int se[2];
    __shared__ float logits[N_CLASSES];
    int g = blockIdx.x, tid = threadIdx.x;
    int c = tid >> 4;                        // plane 0..31
    int q = tid & 15;                        // node stride slot
    if (tid < 2) {
        int target = g + tid;
        int lo = 0, hi = N_NODES;
        while (lo < hi) {
            int mid = (lo + hi) >> 1;
            if (batch[mid] < target) lo = mid + 1; else hi = mid;
        }
        se[tid] = lo;
    }
    __syncthreads();
    int start = se[0], end = se[1];
    float a[8] = {};
    const ushort* pb = h3p + (size_t)c * NP16;
    for (int n = start + q; n < end; n += 16) {
        uint4 v = *(const uint4*)(pb + (size_t)n * 8);
        a[0] += b2f((ushort)(v.x & 0xFFFF)); a[1] += b2f((ushort)(v.x >> 16));
        a[2] += b2f((ushort)(v.y & 0xFFFF)); a[3] += b2f((ushort)(v.y >> 16));
        a[4] += b2f((ushort)(v.z & 0xFFFF)); a[5] += b2f((ushort)(v.z >> 16));
        a[6] += b2f((ushort)(v.w & 0xFFFF)); a[7] += b2f((ushort)(v.w >> 16));
    }
#pragma unroll
    for (int j = 0; j < 8; ++j) part[tid * 8 + j] = a[j];
    __syncthreads();
    if (tid < DIM) {                         // feature f = tid; c = f>>3, j = f&7
        int cc = tid >> 3, jj = tid & 7;
        float s = 0.0f;
#pragma unroll 4
        for (int q2 = 0; q2 < 16; ++q2) s += part[(cc * 16 + q2) * 8 + jj];
        float inv = 1.0f / fmaxf((float)(end - start), 1.0f);
        pooled[tid] = s * inv;
    }
    __syncthreads();
    if (tid < 64) {   // one wave does the head
        int ff = tid * 4;
        float p0 = pooled[ff], p1 = pooled[ff + 1], p2 = pooled[ff + 2], p3 = pooled[ff + 3];
        for (int cl = 0; cl < N_CLASSES; ++cl) {
            float pr = p0 * Wc[(ff + 0) * N_CLASSES + cl] + p1 * Wc[(ff + 1) * N_CLASSES + cl]
                     + p2 * Wc[(ff + 2) * N_CLASSES + cl] + p3 * Wc[(ff + 3) * N_CLASSES + cl];
            for (int st = 32; st > 0; st >>= 1) pr += __shfl_down(pr, st);
            if (tid == 0) logits[cl] = pr + bc[cl];
        }
        if (tid == 0) {
            float mx = logits[0];
            for (int cl = 1; cl < N_CLASSES; ++cl) mx = fmaxf(mx, logits[cl]);
            float sexp = 0.f;
            for (int cl = 0; cl < N_CLASSES; ++cl) sexp += expf(logits[cl] - mx);
            float lse = mx + logf(sexp);
            for (int cl = 0; cl < N_CLASSES; ++cl) {
                out[g * N_CLASSES + cl] = logits[cl];
                out[N_GRAPHS * N_CLASSES + g * N_CLASSES + cl] = logits[cl] - lse;
            }
        }
    }
}

// ---------------- launch ----------------
extern "C" void kernel_launch(void* const* d_in, const int* in_sizes, int n_in,
                              void* d_out, int out_size, void* d_ws, size_t ws_size,
                              hipStream_t stream) {
    const float* x    = (const float*)d_in[0];
    const int*   ei   = (const int*)d_in[1];
    const int*   src  = ei;
    const int*   dst  = ei + N_EDGES;
    const int*   batch= (const int*)d_in[2];
    const float* W1 = (const float*)d_in[3]; const float* b1 = (const float*)d_in[4];
    const float* W2 = (const float*)d_in[5]; const float* b2 = (const float*)d_in[6];
    const float* W3 = (const float*)d_in[7]; const float* b3 = (const float*)d_in[8];
    const float* Wc = (const float*)d_in[9]; const float* bc = (const float*)d_in[10];
    float* out = (float*)d_out;

    char* ws = (char*)d_ws;
    size_t off = 0;
    auto alloc = [&](size_t bytes) -> char* {
        char* p = ws + off;
        off = (off + bytes + 255) & ~(size_t)255;
        return p;
    };
    int*    fill    = (int*)alloc(N_NODES * 4);      // zeroed by k_prep
    ushort* csr16   = (ushort*)alloc((size_t)N_NODES * SLOT * 2);  // 2.56 MB
    ushort* Wt      = (ushort*)alloc((size_t)3 * 65536 * 2);
    ushort* xb      = (ushort*)alloc((size_t)N_NODES * DIM * 2);   // bf16 planes
    ushort* h1      = (ushort*)alloc((size_t)N_NODES * DIM * 2);   // bf16 planes
    unsigned char* h8 = (unsigned char*)alloc((size_t)N_CH * NP8P);  // padded fp8 planes

    // prep: x-convert (313) + Wt (768) + csr prefill (79) + zero fill/pads (20) = 1180
    k_prep<<<1180, 256, 0, stream>>>(x, xb, W1, W2, W3, Wt, csr16, fill, h8);
    // degfill: EXACT R0 shape (ordering preserved)
    k_degfill<<<(N_EDGES + 255) / 256, 256, 0, stream>>>(src, dst, fill, csr16);

    const int agg_grid = N_CH * AGG_SLICES;   // 512 blocks, no LDS, 512 thr
    const int gemm_grid = N_NODES / 32;       // 625 blocks, 2 tiles each

    // conv1: h1 = relu(agg(xb @ W1) + b1)
    k_gemm<<<gemm_grid, 256, 0, stream>>>(xb, Wt, fill, h8);
    k_agg<<<agg_grid, AGG_THR, 0, stream>>>(h8, fill, csr16, b1, nullptr, h1, 0);
    // conv2: xb = relu(h1 + agg(h1 @ W2) + b2)
    k_gemm<<<gemm_grid, 256, 0, stream>>>(h1, Wt + 65536, fill, h8);
    k_agg<<<agg_grid, AGG_THR, 0, stream>>>(h8, fill, csr16, b2, h1, xb, 1);
    // conv3: h1 = agg(xb @ W3) + b3 (no relu), then pool
    k_gemm<<<gemm_grid, 256, 0, stream>>>(xb, Wt + 131072, fill, h8);
    k_agg<<<agg_grid, AGG_THR, 0, stream>>>(h8, fill, csr16, b3, nullptr, h1, 2);

    k_poolfinal<<<N_GRAPHS, 512, 0, stream>>>(h1, batch, Wc, bc, out);
}

// Round 9
// 192.998 us; speedup vs baseline: 1.5912x; 1.5912x over previous
//
#include <hip/hip_runtime.h>
#include <hip/hip_bf16.h>

#define N_NODES   20000
#define N_EDGES   320000
#define DIM       256
#define N_GRAPHS  64
#define N_CLASSES 10
#define N_CH      32                   // feature chunks of 8
#define NP8       (N_NODES * 8)        // bytes per fp8 plane (160000) = LDS stage size
#define NP16      (N_NODES * 8)        // ushorts per bf16 plane (320000 B)
#define AGG_THR   1024                 // 16 waves/block -> 4 waves/SIMD at 1 blk/CU (R5 win)
#define SLOT      64                   // fixed CSR slots per node (max deg+1 = 41 << 64)
#define DUMMY     N_NODES              // pad index -> zeroed row in LDS

// R8 post-mortem: unstaged agg = 48us (L2-latency-bound, 12% VALU) -> LDS staging is
// load-bearing; reverted to R6 structure. R9 adds two bit-neutral shavings:
//  (a) agg staging via global_load_lds width=16 (async DMA, no VGPR round-trip)
//  (b) Wt stored in MFMA fragment order -> gemm B-loads fully coalesced (1KB/instr
//      instead of 16 lines at 512B stride). Same bytes, same order -> bitwise identical.

typedef short  bf16x8 __attribute__((ext_vector_type(8)));
typedef float  f32x4  __attribute__((ext_vector_type(4)));
typedef float  f32x2  __attribute__((ext_vector_type(2)));

__device__ __forceinline__ float b2f(ushort u) {
    return __uint_as_float(((unsigned)u) << 16);
}
__device__ __forceinline__ ushort f2b(float f) {
    unsigned u = __float_as_uint(f);
    u += 0x7FFF + ((u >> 16) & 1);   // round-to-nearest-even
    return (ushort)(u >> 16);
}
// float -> fp8 e4m3 (OCP on gfx950), single value in byte 0
__device__ __forceinline__ unsigned char f2fp8(float f) {
    return (unsigned char)__builtin_amdgcn_cvt_pk_fp8_f32(f, f, 0, false);
}

// ---------------- prep: x-convert (0..312) + W transpose (313..1080) + CSR prefill
// (1081..1159) + zero fill (1160..1179). All branches pure data-parallel writes.
__global__ __launch_bounds__(256) void k_prep(const float* __restrict__ x,
                                              ushort* __restrict__ Xp,
                                              const float* __restrict__ W1,
                                              const float* __restrict__ W2,
                                              const float* __restrict__ W3,
                                              ushort* __restrict__ Wt,
                                              ushort* __restrict__ csr16,
                                              int* __restrict__ fill) {
    if (blockIdx.x < 313) {
        // x fp32 row-major -> bf16 chunk planes [c][node][8], LDS transpose
        __shared__ ushort sh[64 * 260];
        int base = blockIdx.x * 64;
        int t = threadIdx.x;
        int col4 = (t & 63) * 4;
#pragma unroll 4
        for (int it = 0; it < 16; ++it) {
            int r = (t >> 6) + it * 4;
            int n = base + r;
            float4 v = (n < N_NODES) ? *(const float4*)(x + (size_t)n * DIM + col4)
                                     : make_float4(0.f, 0.f, 0.f, 0.f);
            ushort4 o; o.x = f2b(v.x); o.y = f2b(v.y); o.z = f2b(v.z); o.w = f2b(v.w);
            *(ushort4*)(sh + r * 260 + col4) = o;
        }
        __syncthreads();
#pragma unroll 4
        for (int it = 0; it < 8; ++it) {
            int q = it * 256 + t;
            int p = q >> 6, nl = q & 63;
            int n = base + nl;
            if (n < N_NODES) {
                uint2 lo = *(uint2*)(sh + nl * 260 + p * 8);
                uint2 hi = *(uint2*)(sh + nl * 260 + p * 8 + 4);
                uint4 o = make_uint4(lo.x, lo.y, hi.x, hi.y);
                *(uint4*)(Xp + (size_t)p * NP16 + (size_t)n * 8) = o;
            }
        }
    } else if (blockIdx.x < 1081) {
        // Wt in MFMA-fragment order (R9b): for (w, n, k):
        //   frag = (k>>5)*16 + (n>>4)        (k-block kk, n-group ng)
        //   lane = ((k>>3)&3)*16 + (n&15)    (matches gemm's kq/rl lane mapping)
        //   dst  = w*65536 + frag*512 + lane*8 + (k&7)
        // -> each gemm (kk,nb) B-load = 64 lanes x 16B contiguous (1KB coalesced)
        int i = (blockIdx.x - 313) * 256 + threadIdx.x;   // 0..3*65536-1
        int w = i >> 16, r = i & 65535;
        int n = r >> 8, k = r & 255;
        const float* W = (w == 0) ? W1 : (w == 1) ? W2 : W3;
        int dst = (w << 16) + (((k >> 5) * 16 + (n >> 4)) << 9)
                + ((((k >> 3) & 3) * 16 + (n & 15)) << 3) + (k & 7);
        Wt[dst] = f2b(W[k * 256 + n]);
    } else if (blockIdx.x < 1160) {
        // CSR row prefill: slot0 = self-loop, slots 1..63 = DUMMY. degfill overwrites
        // slots 1..deg. A row is 64 ushorts = 128 B = EXACTLY 8 uint4.
        int row = (blockIdx.x - 1081) * 256 + threadIdx.x;
        if (row < N_NODES) {
            uint4* p = (uint4*)(csr16 + (size_t)row * SLOT);
            unsigned dd = (unsigned)DUMMY | ((unsigned)DUMMY << 16);
            uint4 vd = make_uint4(dd, dd, dd, dd);
            p[0] = make_uint4((unsigned)row | ((unsigned)DUMMY << 16), dd, dd, dd);
#pragma unroll
            for (int q = 1; q < 8; ++q) p[q] = vd;
        }
    } else {
        // zero the degree counters (replaces hipMemsetAsync)
        int i = (blockIdx.x - 1160) * 256 + threadIdx.x;  // need 5000 int4
        if (i < N_NODES / 4) ((int4*)fill)[i] = make_int4(0, 0, 0, 0);
    }
}

// ---------------- degfill: EXACT R0 kernel (ordering preserved) ----------------
__global__ void k_degfill(const int* __restrict__ src, const int* __restrict__ dst,
                          int* __restrict__ fill, ushort* __restrict__ csr16) {
    int e = blockIdx.x * 256 + threadIdx.x;
    if (e >= N_EDGES) return;
    int s = src[e], d = dst[e];
    int pos = atomicAdd(&fill[d], 1);
    if (pos < SLOT - 1) csr16[d * SLOT + 1 + pos] = (ushort)s;
}

// ---------------- GEMM: fp8 planes = fp8(dinv[row] * (Xp @ W)), 2 tiles/block ----------------
// B loads from fragment-major Wt: 1KB contiguous per (kk,nb) instruction.
__global__ __launch_bounds__(256) void k_gemm(const ushort* __restrict__ Xp,
                                              const ushort* __restrict__ Wt,
                                              const int* __restrict__ fill,
                                              unsigned char* __restrict__ H8p) {
    int wave = threadIdx.x >> 6;
    int lane = threadIdx.x & 63;
    int m0 = blockIdx.x * 32;            // 625 blocks
    int n0 = wave * 64;
    int rl = lane & 15;
    int kq = (lane >> 4) * 8;

    f32x4 acc0[4] = {}, acc1[4] = {};

#pragma unroll
    for (int kk = 0; kk < 8; ++kk) {
        int k0 = kk * 32;
        int p = (k0 + kq) >> 3;
        const ushort* xp = Xp + (size_t)p * NP16;
        bf16x8 a0 = *(const bf16x8*)(xp + (size_t)(m0 + rl) * 8);
        bf16x8 a1 = *(const bf16x8*)(xp + (size_t)(m0 + 16 + rl) * 8);
#pragma unroll
        for (int nb = 0; nb < 4; ++nb) {
            const ushort* bptr = Wt + (((kk << 4) + (n0 >> 4) + nb) << 9) + (lane << 3);
            bf16x8 b = *(const bf16x8*)bptr;
            acc0[nb] = __builtin_amdgcn_mfma_f32_16x16x32_bf16(a0, b, acc0[nb], 0, 0, 0);
            acc1[nb] = __builtin_amdgcn_mfma_f32_16x16x32_bf16(a1, b, acc1[nb], 0, 0, 0);
        }
    }
    int crow0 = m0 + (lane >> 4) * 4;
    int crow1 = crow0 + 16;
    float d00 = rsqrtf((float)fill[crow0 + 0] + 1.0f);
    float d01 = rsqrtf((float)fill[crow0 + 1] + 1.0f);
    float d02 = rsqrtf((float)fill[crow0 + 2] + 1.0f);
    float d03 = rsqrtf((float)fill[crow0 + 3] + 1.0f);
    float d10 = rsqrtf((float)fill[crow1 + 0] + 1.0f);
    float d11 = rsqrtf((float)fill[crow1 + 1] + 1.0f);
    float d12 = rsqrtf((float)fill[crow1 + 2] + 1.0f);
    float d13 = rsqrtf((float)fill[crow1 + 3] + 1.0f);
#pragma unroll
    for (int nb = 0; nb < 4; ++nb) {
        int col = n0 + nb * 16 + rl;
        size_t base = (size_t)(col >> 3) * NP8 + (col & 7);
        H8p[base + (size_t)(crow0 + 0) * 8] = f2fp8(acc0[nb][0] * d00);
        H8p[base + (size_t)(crow0 + 1) * 8] = f2fp8(acc0[nb][1] * d01);
        H8p[base + (size_t)(crow0 + 2) * 8] = f2fp8(acc0[nb][2] * d02);
        H8p[base + (size_t)(crow0 + 3) * 8] = f2fp8(acc0[nb][3] * d03);
        H8p[base + (size_t)(crow1 + 0) * 8] = f2fp8(acc1[nb][0] * d10);
        H8p[base + (size_t)(crow1 + 1) * 8] = f2fp8(acc1[nb][1] * d11);
        H8p[base + (size_t)(crow1 + 2) * 8] = f2fp8(acc1[nb][2] * d12);
        H8p[base + (size_t)(crow1 + 3) * 8] = f2fp8(acc1[nb][3] * d13);
    }
}

// ---------------- aggregation: LDS-staged fp8 plane (async DMA), packed-f32 accumulate ----------------
__global__ __launch_bounds__(AGG_THR, 1) void k_agg(
    const unsigned char* __restrict__ H8p, const int* __restrict__ fill,
    const ushort* __restrict__ csr16, const float* __restrict__ bias,
    const ushort* __restrict__ prevp, ushort* __restrict__ outp, int mode) {
    extern __shared__ unsigned char lds8[];      // 160016 B: [node][8] fp8 + dummy row
    int tid = threadIdx.x;
    int c  = blockIdx.x & 31;                    // chunk
    int sl = blockIdx.x >> 5;                    // dst slice
    const unsigned char* plane = H8p + (size_t)c * NP8;

    // async global->LDS staging: per-lane k gives lds addr = wave-uniform base + lane*16
    // (exactly the HW write pattern); __syncthreads drains vmcnt.
#pragma unroll
    for (int it = 0; it < (NP8 / 16 + AGG_THR - 1) / AGG_THR; ++it) {
        int k = it * AGG_THR + tid;
        if (k < NP8 / 16)
            __builtin_amdgcn_global_load_lds(
                (const __attribute__((address_space(1))) void*)(plane + (size_t)k * 16),
                (__attribute__((address_space(3))) void*)(lds8 + (size_t)k * 16),
                16, 0, 0);
    }
    if (tid == 0) *(uint2*)(lds8 + (size_t)DUMMY * 8) = make_uint2(0u, 0u);
    __syncthreads();

    int fo = c * 8;
    f32x2 B0 = {bias[fo + 0], bias[fo + 1]}, B1 = {bias[fo + 2], bias[fo + 3]};
    f32x2 B2 = {bias[fo + 4], bias[fo + 5]}, B3 = {bias[fo + 6], bias[fo + 7]};

    int dend = sl * 2500 + 2500;
    for (int d = sl * 2500 + tid; d < dend; d += AGG_THR) {
        int deg = fill[d];
        int len = deg + 1; if (len > SLOT) len = SLOT;
        int rl = (len + 3) & ~3;
        const ushort* row = csr16 + (size_t)d * SLOT;

        uint4 pv;
        if (mode == 1) pv = *(const uint4*)(prevp + (size_t)c * NP16 + (size_t)d * 8);

        f32x2 A0 = {0.f, 0.f}, A1 = {0.f, 0.f}, A2 = {0.f, 0.f}, A3 = {0.f, 0.f};

        // per packed-u32 w = 2 slots; per slot: 4 cvt_pk + 4 pk_add (order preserved)
        auto do2 = [&](unsigned w) {
            int i0 = w & 0xFFFF, i1 = w >> 16;
            uint2 v0 = *(const uint2*)(lds8 + (size_t)i0 * 8);
            uint2 v1 = *(const uint2*)(lds8 + (size_t)i1 * 8);
            f32x2 lo, hi;
            lo = __builtin_amdgcn_cvt_pk_f32_fp8(v0.x, false);
            hi = __builtin_amdgcn_cvt_pk_f32_fp8(v0.x, true);
            A0 += lo; A1 += hi;
            lo = __builtin_amdgcn_cvt_pk_f32_fp8(v0.y, false);
            hi = __builtin_amdgcn_cvt_pk_f32_fp8(v0.y, true);
            A2 += lo; A3 += hi;
            lo = __builtin_amdgcn_cvt_pk_f32_fp8(v1.x, false);
            hi = __builtin_amdgcn_cvt_pk_f32_fp8(v1.x, true);
            A0 += lo; A1 += hi;
            lo = __builtin_amdgcn_cvt_pk_f32_fp8(v1.y, false);
            hi = __builtin_amdgcn_cvt_pk_f32_fp8(v1.y, true);
            A2 += lo; A3 += hi;
        };

        int e = 0;
        for (; e + 8 <= rl; e += 8) {
            uint4 m = *(const uint4*)(row + e);
            do2(m.x); do2(m.y); do2(m.z); do2(m.w);
        }
        if (e < rl) {                           // remaining 4 slots
            uint2 m = *(const uint2*)(row + e);
            do2(m.x); do2(m.y);
        }

        float dv = rsqrtf((float)deg + 1.0f);
        f32x2 DV = {dv, dv};
        A0 = A0 * DV + B0; A1 = A1 * DV + B1;
        A2 = A2 * DV + B2; A3 = A3 * DV + B3;
        if (mode == 1) {
            A0 += (f32x2){b2f((ushort)(pv.x & 0xFFFF)), b2f((ushort)(pv.x >> 16))};
            A1 += (f32x2){b2f((ushort)(pv.y & 0xFFFF)), b2f((ushort)(pv.y >> 16))};
            A2 += (f32x2){b2f((ushort)(pv.z & 0xFFFF)), b2f((ushort)(pv.z >> 16))};
            A3 += (f32x2){b2f((ushort)(pv.w & 0xFFFF)), b2f((ushort)(pv.w >> 16))};
        }
        if (mode != 2) {
            A0[0] = fmaxf(A0[0], 0.f); A0[1] = fmaxf(A0[1], 0.f);
            A1[0] = fmaxf(A1[0], 0.f); A1[1] = fmaxf(A1[1], 0.f);
            A2[0] = fmaxf(A2[0], 0.f); A2[1] = fmaxf(A2[1], 0.f);
            A3[0] = fmaxf(A3[0], 0.f); A3[1] = fmaxf(A3[1], 0.f);
        }
        uint4 o;
        o.x = (unsigned)f2b(A0[0]) | ((unsigned)f2b(A0[1]) << 16);
        o.y = (unsigned)f2b(A1[0]) | ((unsigned)f2b(A1[1]) << 16);
        o.z = (unsigned)f2b(A2[0]) | ((unsigned)f2b(A2[1]) << 16);
        o.w = (unsigned)f2b(A3[0]) | ((unsigned)f2b(A3[1]) << 16);
        *(uint4*)(outp + (size_t)c * NP16 + (size_t)d * 8) = o;
    }
}

// ---------------- fused pool + bounds + head (vectorized: uint4 per node-plane) ----------------
__global__ __launch_bounds__(512) void k_poolfinal(const ushort* __restrict__ h3p,
                                                   const int* __restrict__ batch,
                                                   const float* __restrict__ Wc,
                                                   const float* __restrict__ bc,
                                                   float* __restrict__ out) {
    __shared__ float part[512 * 8];          // 16 KB
    __shared__ float pooled[DIM];
    __shared__ int se[2];
    __shared__ float logits[N_CLASSES];
    int g = blockIdx.x, tid = threadIdx.x;
    int c = tid >> 4;                        // plane 0..31
    int q = tid & 15;                        // node stride slot
    if (tid < 2) {
        int target = g + tid;
        int lo = 0, hi = N_NODES;
        while (lo < hi) {
            int mid = (lo + hi) >> 1;
            if (batch[mid] < target) lo = mid + 1; else hi = mid;
        }
        se[tid] = lo;
    }
    __syncthreads();
    int start = se[0], end = se[1];
    float a[8] = {};
    const ushort* pb = h3p + (size_t)c * NP16;
    for (int n = start + q; n < end; n += 16) {
        uint4 v = *(const uint4*)(pb + (size_t)n * 8);
        a[0] += b2f((ushort)(v.x & 0xFFFF)); a[1] += b2f((ushort)(v.x >> 16));
        a[2] += b2f((ushort)(v.y & 0xFFFF)); a[3] += b2f((ushort)(v.y >> 16));
        a[4] += b2f((ushort)(v.z & 0xFFFF)); a[5] += b2f((ushort)(v.z >> 16));
        a[6] += b2f((ushort)(v.w & 0xFFFF)); a[7] += b2f((ushort)(v.w >> 16));
    }
#pragma unroll
    for (int j = 0; j < 8; ++j) part[tid * 8 + j] = a[j];
    __syncthreads();
    if (tid < DIM) {                         // feature f = tid; c = f>>3, j = f&7
        int cc = tid >> 3, jj = tid & 7;
        float s = 0.0f;
#pragma unroll 4
        for (int q2 = 0; q2 < 16; ++q2) s += part[(cc * 16 + q2) * 8 + jj];
        float inv = 1.0f / fmaxf((float)(end - start), 1.0f);
        pooled[tid] = s * inv;
    }
    __syncthreads();
    if (tid < 64) {   // one wave does the head
        int ff = tid * 4;
        float p0 = pooled[ff], p1 = pooled[ff + 1], p2 = pooled[ff + 2], p3 = pooled[ff + 3];
        for (int cl = 0; cl < N_CLASSES; ++cl) {
            float pr = p0 * Wc[(ff + 0) * N_CLASSES + cl] + p1 * Wc[(ff + 1) * N_CLASSES + cl]
                     + p2 * Wc[(ff + 2) * N_CLASSES + cl] + p3 * Wc[(ff + 3) * N_CLASSES + cl];
            for (int st = 32; st > 0; st >>= 1) pr += __shfl_down(pr, st);
            if (tid == 0) logits[cl] = pr + bc[cl];
        }
        if (tid == 0) {
            float mx = logits[0];
            for (int cl = 1; cl < N_CLASSES; ++cl) mx = fmaxf(mx, logits[cl]);
            float sexp = 0.f;
            for (int cl = 0; cl < N_CLASSES; ++cl) sexp += expf(logits[cl] - mx);
            float lse = mx + logf(sexp);
            for (int cl = 0; cl < N_CLASSES; ++cl) {
                out[g * N_CLASSES + cl] = logits[cl];
                out[N_GRAPHS * N_CLASSES + g * N_CLASSES + cl] = logits[cl] - lse;
            }
        }
    }
}

// ---------------- launch ----------------
extern "C" void kernel_launch(void* const* d_in, const int* in_sizes, int n_in,
                              void* d_out, int out_size, void* d_ws, size_t ws_size,
                              hipStream_t stream) {
    const float* x    = (const float*)d_in[0];
    const int*   ei   = (const int*)d_in[1];
    const int*   src  = ei;
    const int*   dst  = ei + N_EDGES;
    const int*   batch= (const int*)d_in[2];
    const float* W1 = (const float*)d_in[3]; const float* b1 = (const float*)d_in[4];
    const float* W2 = (const float*)d_in[5]; const float* b2 = (const float*)d_in[6];
    const float* W3 = (const float*)d_in[7]; const float* b3 = (const float*)d_in[8];
    const float* Wc = (const float*)d_in[9]; const float* bc = (const float*)d_in[10];
    float* out = (float*)d_out;

    // allow 160 KB dynamic LDS for k_agg (idempotent, capture-safe)
    hipFuncSetAttribute(reinterpret_cast<const void*>(k_agg),
                        hipFuncAttributeMaxDynamicSharedMemorySize, NP8 + 16);

    char* ws = (char*)d_ws;
    size_t off = 0;
    auto alloc = [&](size_t bytes) -> char* {
        char* p = ws + off;
        off = (off + bytes + 255) & ~(size_t)255;
        return p;
    };
    int*    fill    = (int*)alloc(N_NODES * 4);      // zeroed by k_prep
    ushort* csr16   = (ushort*)alloc((size_t)N_NODES * SLOT * 2);  // 2.56 MB
    ushort* Wt      = (ushort*)alloc((size_t)3 * 65536 * 2);
    ushort* xb      = (ushort*)alloc((size_t)N_NODES * DIM * 2);   // bf16 planes
    ushort* h1      = (ushort*)alloc((size_t)N_NODES * DIM * 2);   // bf16 planes
    unsigned char* h8 = (unsigned char*)alloc((size_t)N_NODES * DIM);  // fp8 planes

    // prep: x-convert (313) + Wt (768) + csr prefill (79) + zero fill (20) = 1180 blocks
    k_prep<<<1180, 256, 0, stream>>>(x, xb, W1, W2, W3, Wt, csr16, fill);
    // degfill: EXACT R0 shape (ordering preserved)
    k_degfill<<<(N_EDGES + 255) / 256, 256, 0, stream>>>(src, dst, fill, csr16);

    const int agg_grid = N_CH * 8;         // 256 blocks, 1/CU, 160 KB LDS, 1024 thr
    const int gemm_grid = N_NODES / 32;    // 625 blocks, 2 tiles each

    // conv1: h1 = relu(agg(xb @ W1) + b1)
    k_gemm<<<gemm_grid, 256, 0, stream>>>(xb, Wt, fill, h8);
    k_agg<<<agg_grid, AGG_THR, NP8 + 16, stream>>>(h8, fill, csr16, b1, nullptr, h1, 0);
    // conv2: xb = relu(h1 + agg(h1 @ W2) + b2)
    k_gemm<<<gemm_grid, 256, 0, stream>>>(h1, Wt + 65536, fill, h8);
    k_agg<<<agg_grid, AGG_THR, NP8 + 16, stream>>>(h8, fill, csr16, b2, h1, xb, 1);
    // conv3: h1 = agg(xb @ W3) + b3 (no relu), then pool
    k_gemm<<<gemm_grid, 256, 0, stream>>>(xb, Wt + 131072, fill, h8);
    k_agg<<<agg_grid, AGG_THR, NP8 + 16, stream>>>(h8, fill, csr16, b3, nullptr, h1, 2);

    k_poolfinal<<<N_GRAPHS, 512, 0, stream>>>(h1, batch, Wc, bc, out);
}